// Round 3
// baseline (940.223 us; speedup 1.0000x reference)
//
#include <hip/hip_runtime.h>
#include <hip/hip_bf16.h>

// Linear recurrence h_t = x_t@W + h_{t-1}@R, parallel scan.
// Big kernels (xw / local-combine / fix0) use M=64 tiles with the state kept
// in LDS as a bf16 hi/lo PAIR (split once at write time), read via swizzled
// ds_read_b128. 16 waves, each owning 2 n-tiles (B-frags read exactly once).
// Tree/chain kernels unchanged from R2.

typedef float f32x4 __attribute__((ext_vector_type(4)));
typedef __bf16 bf16x8 __attribute__((ext_vector_type(8)));

#define TDIM 2048L
#define UDIM 512L
#define ST 16384L       // elems per [32,512] state
#define PST 32768       // elems per [64,512] plane
#define TS 262144L      // elems per frag term
#define FE 786432L      // elems per 3-term frag matrix

__device__ __forceinline__ f32x4 mfma16(bf16x8 a, bf16x8 b, f32x4 c) {
  return __builtin_amdgcn_mfma_f32_16x16x32_bf16(a, b, c, 0, 0, 0);
}

// bf16 plane [64][512]: 16B-block swizzle -> 2-way (free) on frag reads.
__device__ __forceinline__ int pidx(int row, int colblk) {
  return row * 512 + ((colblk ^ (row & 7)) << 3);
}

// fp32 [32][512] swizzle (kept for k_sq only).
__device__ __forceinline__ int hidx(int row, int col) {
  return row * 512 + (col ^ ((row & 7) << 3));
}

// Stage a contiguous fp32 [64][512] block into hi/lo planes.
__device__ __forceinline__ void stage_pair(const float* __restrict__ src,
                                           __bf16* Phi, __bf16* Plo) {
  for (int i = threadIdx.x; i < 4096; i += 1024) {
    const int row = i >> 6, cb = i & 63;
    const f32x4 v0 = *(const f32x4*)(src + row * 512 + cb * 8);
    const f32x4 v1 = *(const f32x4*)(src + row * 512 + cb * 8 + 4);
    bf16x8 hv, lv;
#pragma unroll
    for (int j = 0; j < 4; ++j) {
      const float a = v0[j];
      const __bf16 ha = (__bf16)a;
      hv[j] = ha; lv[j] = (__bf16)(a - (float)ha);
      const float b = v1[j];
      const __bf16 hb = (__bf16)b;
      hv[j + 4] = hb; lv[j + 4] = (__bf16)(b - (float)hb);
    }
    const int o = pidx(row, cb);
    *(bf16x8*)(Phi + o) = hv;
    *(bf16x8*)(Plo + o) = lv;
  }
}

// One step on the pair planes: h_new = (HAS_H ? h@B : 0) + (HAS_ADD ? xw : 0).
// 16 waves; wave w owns n-tiles 2w,2w+1; mt=0..3 covers all 64 rows
// (rows 0-31 = chunk A, 32-63 = chunk B).
// GMODE: 0 none, 1 = [B,T,U] layout at t=(gA|gB), 2 = contiguous [64][512].
template <int NTERM, int NPROD, bool HAS_H, bool HAS_ADD, int GMODE, bool WP>
__device__ __forceinline__ void pstep(__bf16* Phi, __bf16* Plo,
                                      const __bf16* __restrict__ bfrag,
                                      const float* __restrict__ addbase,
                                      long tA, long tB,
                                      float* gdst, long gA, long gB) {
  const int tid = threadIdx.x, l = tid & 63, w = tid >> 6, g = l >> 4, li = l & 15;

  f32x4 addv[4][2];
  if (HAS_ADD) {
#pragma unroll
    for (int mt = 0; mt < 4; ++mt) {
      const long t = (mt < 2) ? tA : tB;
#pragma unroll
      for (int q = 0; q < 2; ++q) {
        const int col = (w * 2 + q) * 16 + li;
#pragma unroll
        for (int r = 0; r < 4; ++r) {
          const int row = mt * 16 + g * 4 + r;
          addv[mt][q][r] = addbase[(long)(row & 31) * (TDIM * UDIM) + t * UDIM + col];
        }
      }
    }
  }

  f32x4 acc[4][2] = {};
  if (HAS_H) {
#pragma unroll 2
    for (int kk = 0; kk < 16; ++kk) {
      bf16x8 b[NTERM][2];
#pragma unroll
      for (int q = 0; q < 2; ++q) {
        const long fo = (((long)(w * 2 + q) * 16 + kk) * 64 + l) * 8;
#pragma unroll
        for (int t = 0; t < NTERM; ++t)
          b[t][q] = *(const bf16x8*)(bfrag + (long)t * TS + fo);
      }
#pragma unroll
      for (int mt = 0; mt < 4; ++mt) {
        const int o = pidx(mt * 16 + li, kk * 4 + g);
        const bf16x8 a1 = *(const bf16x8*)(Phi + o);
        const bf16x8 a2 = *(const bf16x8*)(Plo + o);
#pragma unroll
        for (int q = 0; q < 2; ++q) {
          acc[mt][q] = mfma16(a1, b[0][q], acc[mt][q]);
          acc[mt][q] = mfma16(a1, b[1][q], acc[mt][q]);
          if (NPROD >= 3) acc[mt][q] = mfma16(a2, b[0][q], acc[mt][q]);
          if (NPROD >= 4) acc[mt][q] = mfma16(a1, b[NTERM - 1][q], acc[mt][q]);
        }
      }
    }
  }

  __syncthreads();  // plane reads done before overwrite
#pragma unroll
  for (int mt = 0; mt < 4; ++mt) {
    const long gt = (mt < 2) ? gA : gB;
#pragma unroll
    for (int q = 0; q < 2; ++q) {
      const int col = (w * 2 + q) * 16 + li;
#pragma unroll
      for (int r = 0; r < 4; ++r) {
        float v = HAS_H ? acc[mt][q][r] : 0.0f;
        if (HAS_ADD) v += addv[mt][q][r];
        const int row = mt * 16 + g * 4 + r;
        if (WP) {
          const __bf16 hi = (__bf16)v;
          const int o = pidx(row, col >> 3) + (col & 7);
          Phi[o] = hi;
          Plo[o] = (__bf16)(v - (float)hi);
        }
        if (GMODE == 1)
          gdst[(long)(row & 31) * (TDIM * UDIM) + gt * UDIM + col] = v;
        else if (GMODE == 2)
          gdst[(long)row * 512 + col] = v;
      }
    }
  }
  if (WP) __syncthreads();
}

// ---- kernels --------------------------------------------------------------

// Split fp32 512x512 into 3 bf16 terms in MFMA B-fragment order.
__global__ __launch_bounds__(512) void k_split(const float* __restrict__ m,
                                               __bf16* __restrict__ f) {
  const int idx = blockIdx.x * 512 + threadIdx.x;
  const int j = idx & 7, l = (idx >> 3) & 63, kk = (idx >> 9) & 15, nt = idx >> 13;
  const int k = kk * 32 + (l >> 4) * 8 + j;
  const int n = nt * 16 + (l & 15);
  const float v = m[k * 512 + n];
  const __bf16 t1 = (__bf16)v;
  const float r1 = v - (float)t1;
  const __bf16 t2 = (__bf16)r1;
  f[idx] = t1;
  f[TS + idx] = t2;
  f[2 * TS + idx] = (__bf16)(r1 - (float)t2);
}

// xW: 64-row tiles, 2-term W, 3 products.
__global__ __launch_bounds__(1024) void k_xw(const float* __restrict__ x,
                                             const __bf16* __restrict__ wf,
                                             float* __restrict__ out) {
  __shared__ __bf16 Phi[PST], Plo[PST];
  const long blk = blockIdx.x;
  stage_pair(x + blk * PST, Phi, Plo);
  __syncthreads();
  pstep<2, 3, true, false, 2, false>(Phi, Plo, wf, nullptr, 0, 0,
                                     out + blk * PST, 0, 0);
}

// Level-0 up-sweep: block handles chunks c0=2b, c0+1; S[c] = chunk combine.
__global__ __launch_bounds__(1024) void k_local(const float* __restrict__ xw,
                                                const __bf16* __restrict__ rf,
                                                float* __restrict__ sout) {
  __shared__ __bf16 Phi[PST], Plo[PST];
  const long c0 = (long)blockIdx.x * 2;
  pstep<3, 4, false, true, 0, true>(Phi, Plo, rf, xw, c0 * 8, (c0 + 1) * 8,
                                    nullptr, 0, 0);
  for (int j = 1; j < 7; ++j)
    pstep<3, 4, true, true, 0, true>(Phi, Plo, rf, xw, c0 * 8 + j,
                                     (c0 + 1) * 8 + j, nullptr, 0, 0);
  pstep<3, 4, true, true, 2, false>(Phi, Plo, rf, xw, c0 * 8 + 7,
                                    (c0 + 1) * 8 + 7, sout + c0 * ST, 0, 0);
}

// Final pass: block handles chunks c0=2b, c0+1 from corrected entries.
__global__ __launch_bounds__(1024) void k_fix0(const float* __restrict__ e0,
                                               float* out,
                                               const __bf16* __restrict__ rf) {
  __shared__ __bf16 Phi[PST], Plo[PST];
  const long c0 = (long)blockIdx.x * 2;
  stage_pair(e0 + c0 * ST, Phi, Plo);
  __syncthreads();
  for (int j = 0; j < 7; ++j)
    pstep<2, 3, true, true, 1, true>(Phi, Plo, rf, out, c0 * 8 + j,
                                     (c0 + 1) * 8 + j, out, c0 * 8 + j,
                                     (c0 + 1) * 8 + j);
  pstep<2, 3, true, true, 1, false>(Phi, Plo, rf, out, c0 * 8 + 7,
                                    (c0 + 1) * 8 + 7, out, c0 * 8 + 7,
                                    (c0 + 1) * 8 + 7);
}

// ---- tree / chain kernels (unchanged from R2) -----------------------------

__device__ __forceinline__ f32x4 one_mm(const float* __restrict__ a,
                                        const __bf16* __restrict__ bf,
                                        int mt, int ntg) {
  const int tid = threadIdx.x, l = tid & 63, g = (l >> 4) & 3, li = l & 15;
  f32x4 acc = {};
#pragma unroll 2
  for (int kk = 0; kk < 16; ++kk) {
    const long fo = (((long)ntg * 16 + kk) * 64 + l) * 8;
    const bf16x8 b0 = *(const bf16x8*)(bf + fo);
    const bf16x8 b1 = *(const bf16x8*)(bf + TS + fo);
    const bf16x8 b2 = *(const bf16x8*)(bf + 2 * TS + fo);
    bf16x8 a1, a2;
    const float* p = a + (long)(mt * 16 + li) * 512 + kk * 32 + g * 8;
#pragma unroll
    for (int j = 0; j < 8; ++j) {
      const float v = p[j];
      const __bf16 hi = (__bf16)v;
      a1[j] = hi;
      a2[j] = (__bf16)(v - (float)hi);
    }
    acc = mfma16(a1, b0, acc);
    acc = mfma16(a1, b1, acc);
    acc = mfma16(a2, b0, acc);
    acc = mfma16(a1, b2, acc);
  }
  return acc;
}

// Squaring-chain: out = A @ Bfrag(A); writes fp32 + fused 3-term frag split.
__global__ __launch_bounds__(512) void k_sq(const float* __restrict__ a,
                                            const __bf16* __restrict__ bf,
                                            float* __restrict__ of32,
                                            __bf16* __restrict__ ofr) {
  __shared__ float hbuf[32 * 512];
  const int b = blockIdx.x, rg = b >> 3, cg = b & 7;
  const int tid = threadIdx.x, l = tid & 63, w = tid >> 6, g = l >> 4, li = l & 15;
  const float* src = a + (long)rg * ST;
  for (int i = tid; i < 4096; i += 512) {
    const int flat = i * 4, row = flat >> 9, col = flat & 511;
    *(f32x4*)&hbuf[hidx(row, col)] = *(const f32x4*)&src[flat];
  }
  __syncthreads();
  const int mt = w >> 2, q = w & 3, ntg = cg * 4 + q;
  f32x4 acc = {};
#pragma unroll 2
  for (int kk = 0; kk < 16; ++kk) {
    const long fo = (((long)ntg * 16 + kk) * 64 + l) * 8;
    const bf16x8 b0 = *(const bf16x8*)(bf + fo);
    const bf16x8 b1 = *(const bf16x8*)(bf + TS + fo);
    const bf16x8 b2 = *(const bf16x8*)(bf + 2 * TS + fo);
    bf16x8 a1, a2;
    const float* pp = &hbuf[hidx(mt * 16 + li, kk * 32 + g * 8)];
#pragma unroll
    for (int j = 0; j < 8; ++j) {
      const float v = pp[j];
      const __bf16 hi = (__bf16)v;
      a1[j] = hi;
      a2[j] = (__bf16)(v - (float)hi);
    }
    acc = mfma16(a1, b0, acc);
    acc = mfma16(a1, b1, acc);
    acc = mfma16(a2, b0, acc);
    acc = mfma16(a1, b2, acc);
  }
  const int n = ntg * 16 + li;
#pragma unroll
  for (int r = 0; r < 4; ++r) {
    const int k = rg * 32 + mt * 16 + g * 4 + r;
    const float v = acc[r];
    of32[(long)k * 512 + n] = v;
    const __bf16 t1 = (__bf16)v;
    const float r1 = v - (float)t1;
    const __bf16 t2 = (__bf16)r1;
    const long fi = (((long)(n >> 4) * 16 + (k >> 5)) * 64 + ((k >> 3) & 3) * 16 + (n & 15)) * 8 + (k & 7);
    ofr[fi] = t1;
    ofr[TS + fi] = t2;
    ofr[2 * TS + fi] = (__bf16)(r1 - (float)t2);
  }
}

// Tree up-stage: out[p] = in[2p] @ M + in[2p+1]. Grid = pairs*8 (col-split).
__global__ __launch_bounds__(512) void k_pair(const float* __restrict__ in,
                                              const __bf16* __restrict__ bf,
                                              float* __restrict__ outb) {
  const int p = blockIdx.x >> 3, cs = blockIdx.x & 7;
  const int tid = threadIdx.x, l = tid & 63, w = tid >> 6, g = l >> 4, li = l & 15;
  const int mt = w >> 2, ntg = cs * 4 + (w & 3);
  const f32x4 acc = one_mm(in + (long)(2 * p) * ST, bf, mt, ntg);
  const float* addp = in + (long)(2 * p + 1) * ST;
  float* outp = outb + (long)p * ST;
  const int col = ntg * 16 + li;
#pragma unroll
  for (int r = 0; r < 4; ++r) {
    const int row = mt * 16 + g * 4 + r;
    outp[(long)row * 512 + col] = acc[r] + addp[(long)row * 512 + col];
  }
}

// Tree down-stage (in place into child-level buffer).
__global__ __launch_bounds__(512) void k_down(const float* __restrict__ epar,
                                              float* __restrict__ ulev,
                                              const __bf16* __restrict__ bf) {
  const int p = blockIdx.x >> 3, cs = blockIdx.x & 7;
  const int tid = threadIdx.x, l = tid & 63, w = tid >> 6, g = l >> 4, li = l & 15;
  const int mt = w >> 2, ntg = cs * 4 + (w & 3);
  const f32x4 acc = one_mm(epar + (long)p * ST, bf, mt, ntg);
  float* evp = ulev + (long)(2 * p) * ST;
  float* outp = ulev + (long)(2 * p + 1) * ST;
  const int col = ntg * 16 + li;
  float cp[4];
#pragma unroll
  for (int r = 0; r < 4; ++r) {
    const int row = mt * 16 + g * 4 + r;
    const long off = (long)row * 512 + col;
    cp[r] = epar[(long)p * ST + off];
    outp[off] = acc[r] + evp[off];
  }
  __syncthreads();
#pragma unroll
  for (int r = 0; r < 4; ++r) {
    const int row = mt * 16 + g * 4 + r;
    evp[(long)row * 512 + col] = cp[r];
  }
}

extern "C" void kernel_launch(void* const* d_in, const int* in_sizes, int n_in,
                              void* d_out, int out_size, void* d_ws, size_t ws_size,
                              hipStream_t stream) {
  (void)in_sizes; (void)n_in; (void)out_size; (void)ws_size;
  const float* x  = (const float*)d_in[0];
  const float* W  = (const float*)d_in[1];
  const float* R  = (const float*)d_in[2];
  const float* h0 = (const float*)d_in[3];
  float* out = (float*)d_out;

  __bf16* F  = (__bf16*)d_ws;          // F[i] = frags of R^(2^i), i=0..10
  __bf16* Fw = F + 11 * FE;            // frags of W
  float* P1 = (float*)(Fw + FE);
  float* P2 = P1 + TS;
  float* Sbuf = P2 + TS;               // 256 chunk sums -> entries E0
  float* Ub[8];
  {
    float* up = Sbuf + 256 * ST;
    for (int k = 1; k <= 7; ++k) { Ub[k] = up; up += (1L << (8 - k)) * ST; }
  }

  k_split<<<512, 512, 0, stream>>>(W, Fw);
  k_split<<<512, 512, 0, stream>>>(R, F);

  k_xw<<<1024, 1024, 0, stream>>>(x, Fw, out);
  k_local<<<128, 1024, 0, stream>>>(out, F, Sbuf);

  // squaring chain: R^2 .. R^1024, fused frag split
  {
    const float* pin = R;
    for (int i = 1; i <= 10; ++i) {
      float* po = (i & 1) ? P1 : P2;
      k_sq<<<128, 512, 0, stream>>>(pin, F + (long)(i - 1) * FE, po, F + (long)i * FE);
      pin = po;
    }
  }

  // tree up-sweep over 256 chunk sums (stage k uses M^(2^(k-1)) = F[k+2])
  for (int k = 1; k <= 7; ++k) {
    const float* inp = (k == 1) ? Sbuf : Ub[k - 1];
    k_pair<<<(1 << (8 - k)) * 8, 512, 0, stream>>>(inp, F + (long)(k + 2) * FE, Ub[k]);
  }

  // down-sweep: entries, in place into each child level (E0 lands in Sbuf)
  k_down<<<8, 512, 0, stream>>>(h0, Ub[7], F + 10L * FE);
  for (int k = 7; k >= 1; --k) {
    float* ul = (k == 1) ? Sbuf : Ub[k - 1];
    k_down<<<(1 << (8 - k)) * 8, 512, 0, stream>>>(Ub[k], ul, F + (long)(k + 2) * FE);
  }

  k_fix0<<<128, 1024, 0, stream>>>(Sbuf, out, F);
}